// Round 5
// baseline (316.554 us; speedup 1.0000x reference)
//
#include <hip/hip_runtime.h>
#include <hip/hip_cooperative_groups.h>

namespace cg = cooperative_groups;

// x: [128][256][256][3] fp32, C: [768][4][256][4] fp32 -> [3072][1024]
// out[b,kl,hw] = S_x[b,hw] * S_C[kl]  (einsum factorizes; no shared labels)
//
// ws layout (floats), every element overwritten each call (no zeroing):
//   rowsum[512][8][768]  - per quarter-image, per h-class row sums (12.6 MB)
//   psC[96][1024]        - C column partials
//   sC[1024], sx[128*64] - final factors

#define ROWSUM_ELEMS (512 * 8 * 768)
#define PSC_ELEMS    (96 * 1024)

// ---------- A: C column partial sums (independent, regular launch) ----------
__global__ __launch_bounds__(256) void reduce_C_part(const float* __restrict__ C,
                                                     float4* __restrict__ psC) {
    const int p = blockIdx.x;          // 96 row-groups of 32
    const int t = threadIdx.x;         // 256 float4 cols
    const float4* row = (const float4*)C + (size_t)p * 32 * 256 + t;
    float4 a = {0.f, 0.f, 0.f, 0.f};
#pragma unroll
    for (int r = 0; r < 32; ++r) {
        float4 v = row[(size_t)r * 256];
        a.x += v.x; a.y += v.y; a.z += v.z; a.w += v.w;
    }
    psC[p * 256 + t] = a;
}

// ---------- Fused cooperative kernel: P1 stream+bin, P2 finalize, P3 expand ----------
// 512 blocks x 384 threads = 2 blocks/CU (co-resident: 768 thr, ~1.3KB LDS, low VGPR).
__global__ __launch_bounds__(384, 3) void fused(const float4* __restrict__ x4,
                                                float4* __restrict__ rowsum4,
                                                const float* __restrict__ psC,
                                                float* __restrict__ sx,
                                                float* __restrict__ sC,
                                                float4* __restrict__ out4) {
    cg::grid_group grid = cg::this_grid();
    const int blk = blockIdx.x;        // [0, 512)
    const int t   = threadIdx.x;       // [0, 384)
    __shared__ float lds[64][5];

    // ---- P1: contiguous quarter-image stream (64 rows = 12288 float4 = 192KB).
    // 384 thr x float4 = 2 rows/step; r = t/192 (wave-uniform), c4 = t%192.
    // Step m covers rows 2m+r -> h = (2m+r)&7; acc slot j = m&3 (h = 2j+r).
    // Store offset j*384 + r*192 + c4 == (2j+r)*192 + c4 -> layout [blk][h][c4].
    {
        const int b = blk >> 2, q = blk & 3;
        const float4* base = x4 + (size_t)b * 49152 + q * 12288 + t;
        float4 acc[4];
#pragma unroll
        for (int j = 0; j < 4; ++j) acc[j] = (float4){0.f, 0.f, 0.f, 0.f};
#pragma unroll
        for (int m = 0; m < 32; ++m) {
            float4 v = base[m * 384];
            const int j = m & 3;
            acc[j].x += v.x; acc[j].y += v.y; acc[j].z += v.z; acc[j].w += v.w;
        }
        const int r = t / 192, c4 = t % 192;
        float4* dst = rowsum4 + (size_t)blk * 1536 + r * 192 + c4;
#pragma unroll
        for (int j = 0; j < 4; ++j) dst[j * 384] = acc[j];
    }
    grid.sync();

    // ---- P2: blocks 0..127 bin rowsum[b] -> sx[b][64]; blocks 128..135 fold sC.
    if (blk < 128) {
        if (t < 256) {
            const int hw = t & 63, part = t >> 6;       // part = quarter q
            const int h = hw >> 3, w = hw & 7;
            const float* rp = (const float*)rowsum4
                            + (((size_t)blk * 4 + part) * 8 + h) * 768 + 3 * w;
            float s = 0.f;
#pragma unroll
            for (int g = 0; g < 32; ++g)                // FULL width: 32 patches
                s += rp[24 * g] + rp[24 * g + 1] + rp[24 * g + 2];
            lds[hw][part] = s;
        }
        __syncthreads();
        if (t < 64) sx[blk * 64 + t] = lds[t][0] + lds[t][1] + lds[t][2] + lds[t][3];
    } else if (blk < 136) {
        if (t < 128) {
            const int col = (blk - 128) * 128 + t;
            float s = 0.f;
#pragma unroll
            for (int p = 0; p < 96; ++p) s += psC[p * 1024 + col];
            sC[col] = s;
        }
    }
    grid.sync();

    // ---- P3: expand. 196608 threads = 12 images/pass; rem constant per thread.
    {
        const int g0  = blk * 384 + t;
        const int rem = g0 & 16383;        // float4 index within an image
        const int b0  = g0 >> 14;          // [0, 12)
        const float s = sC[rem >> 4];
        const float4* sx4 = (const float4*)sx;
#pragma unroll
        for (int i = 0; i < 11; ++i) {
            const int b = b0 + 12 * i;
            if (b < 128) {
                const float4 v = sx4[b * 16 + (rem & 15)];
                float4 rr;
                rr.x = v.x * s; rr.y = v.y * s; rr.z = v.z * s; rr.w = v.w * s;
                out4[(size_t)b * 16384 + rem] = rr;
            }
        }
    }
}

extern "C" void kernel_launch(void* const* d_in, const int* in_sizes, int n_in,
                              void* d_out, int out_size, void* d_ws, size_t ws_size,
                              hipStream_t stream) {
    const float* x = (const float*)d_in[0];
    const float* C = (const float*)d_in[1];

    float* rowsum = (float*)d_ws;
    float* psC    = rowsum + ROWSUM_ELEMS;
    float* sC     = psC + PSC_ELEMS;
    float* sx     = sC + 1024;

    reduce_C_part<<<dim3(96), 256, 0, stream>>>(C, (float4*)psC);

    const float4* x4 = (const float4*)x;
    float4* rowsum4  = (float4*)rowsum;
    float4* out4     = (float4*)d_out;
    const float* psCc = psC;
    void* args[] = {(void*)&x4, (void*)&rowsum4, (void*)&psCc,
                    (void*)&sx, (void*)&sC, (void*)&out4};
    hipLaunchCooperativeKernel((const void*)fused, dim3(512), dim3(384),
                               args, 0, stream);
}

// Round 6
// 182.191 us; speedup vs baseline: 1.7375x; 1.7375x over previous
//
#include <hip/hip_runtime.h>

typedef float f4 __attribute__((ext_vector_type(4)));

// x: [128][256][256][3] fp32 (= [128][49152] float4), C: [3072][1024] fp32
// out[b,kl,hw] = S_x[b,hw] * S_C[kl]  (einsum factorizes; no shared labels)
//
// ws (floats), all overwritten each call: psx[1536][64] | psC[96][1024] | sC[1024] | sx[128][64]

#define PSX_ELEMS (1536 * 64)
#define PSC_ELEMS (96 * 1024)

// ---------- K1: x comb reduction (blocks 0..1535) + C partials (1536..1631) ----------
// x-block bk: b = bk/12, seg = bk%12. Thread t loads F = b*49152 + seg*256 + t + 3072k,
// k<16 (stride 3072 f4 = 16 rows): h = ((seg*256+t)/192)%8 and row-phase
// p0 = (4*(seg*256+t))%24 are CONSTANT per thread -> one f4 accumulator, classify once.
__global__ __launch_bounds__(256) void k1_reduce(const f4* __restrict__ x4,
                                                 float* __restrict__ psx,
                                                 f4* __restrict__ psC) {
    const int bk = blockIdx.x, t = threadIdx.x;

    if (bk < 1536) {
        const int b = bk / 12, seg = bk % 12;
        const int off = seg * 256 + t;
        const f4* xb = x4 + (size_t)b * 49152 + off;

        f4 acc0 = {0.f,0.f,0.f,0.f}, acc1 = {0.f,0.f,0.f,0.f};
        f4 acc2 = {0.f,0.f,0.f,0.f}, acc3 = {0.f,0.f,0.f,0.f};
#pragma unroll
        for (int k = 0; k < 16; k += 4) {
            f4 v0 = __builtin_nontemporal_load(xb + (size_t)(k + 0) * 3072);
            f4 v1 = __builtin_nontemporal_load(xb + (size_t)(k + 1) * 3072);
            f4 v2 = __builtin_nontemporal_load(xb + (size_t)(k + 2) * 3072);
            f4 v3 = __builtin_nontemporal_load(xb + (size_t)(k + 3) * 3072);
            acc0 += v0; acc1 += v1; acc2 += v2; acc3 += v3;
        }
        const f4 a = (acc0 + acc1) + (acc2 + acc3);

        __shared__ float bins[64];
        if (t < 64) bins[t] = 0.f;
        __syncthreads();

        const int h  = (off / 192) & 7;
        const int p0 = (4 * off) % 24;                 // position of a.x within w-period
        atomicAdd(&bins[h * 8 + ((p0 + 0) % 24) / 3], a.x);
        atomicAdd(&bins[h * 8 + ((p0 + 1) % 24) / 3], a.y);
        atomicAdd(&bins[h * 8 + ((p0 + 2) % 24) / 3], a.z);
        atomicAdd(&bins[h * 8 + ((p0 + 3) % 24) / 3], a.w);
        __syncthreads();

        if (t < 64) psx[(size_t)bk * 64 + t] = bins[t];
    } else {
        // C column partials: 96 blocks, 32 rows each, 256 f4 cols
        const int p = bk - 1536;
        const f4* row = (const f4*)psC;  // unused alias silencer
        (void)row;
        const f4* Crow = ((const f4*)nullptr);
        (void)Crow;
        // real pointer passed via psC? no -- C comes in via x4? No: separate param needed.
        // (handled below -- see k1_reduce_C)
    }
}

// C partials kept as their own tiny kernel to keep k1 signatures clean.
__global__ __launch_bounds__(256) void k1_reduce_C(const f4* __restrict__ C4,
                                                   f4* __restrict__ psC) {
    const int p = blockIdx.x, t = threadIdx.x;
    const f4* row = C4 + (size_t)p * 32 * 256 + t;
    f4 a = {0.f,0.f,0.f,0.f};
#pragma unroll
    for (int r = 0; r < 32; ++r) a += row[(size_t)r * 256];
    psC[p * 256 + t] = a;
}

// ---------- K2: finalize sx (fold 12 segs) and sC (fold 96 partials) ----------
__global__ __launch_bounds__(128) void k2_finalize(const float* __restrict__ psx,
                                                   const float* __restrict__ psC,
                                                   float* __restrict__ sx,
                                                   float* __restrict__ sC) {
    const int blk = blockIdx.x, t = threadIdx.x;
    if (blk < 128) {
        if (t < 64) {
            float s = 0.f;
#pragma unroll
            for (int seg = 0; seg < 12; ++seg)
                s += psx[((size_t)blk * 12 + seg) * 64 + t];
            sx[blk * 64 + t] = s;
        }
    } else {
        const int col = (blk - 128) * 128 + t;
        float s = 0.f;
#pragma unroll
        for (int p = 0; p < 96; ++p) s += psC[p * 1024 + col];
        sC[col] = s;
    }
}

// ---------- K3: outer-product expansion, NT stores ----------
__global__ __launch_bounds__(256) void k3_expand(const float* __restrict__ sx,
                                                 const float* __restrict__ sC,
                                                 f4* __restrict__ out4) {
    const int b = blockIdx.y, bx = blockIdx.x, t = threadIdx.x;
    __shared__ float sxl[64];
    __shared__ float sCl[64];
    if (t < 64)       sxl[t]      = sx[b * 64 + t];
    else if (t < 128) sCl[t - 64] = sC[bx * 64 + (t - 64)];
    __syncthreads();

    const f4 v = ((const f4*)sxl)[t & 15];
    f4* ob = out4 + (size_t)b * 16384 + bx * 1024 + t;
#pragma unroll
    for (int u = 0; u < 4; ++u) {
        const float s = sCl[(t >> 4) + 16 * u];
        f4 rr = v * s;
        __builtin_nontemporal_store(rr, ob + 256 * u);
    }
}

extern "C" void kernel_launch(void* const* d_in, const int* in_sizes, int n_in,
                              void* d_out, int out_size, void* d_ws, size_t ws_size,
                              hipStream_t stream) {
    const f4* x4 = (const f4*)d_in[0];
    const f4* C4 = (const f4*)d_in[1];

    float* psx = (float*)d_ws;
    float* psC = psx + PSX_ELEMS;
    float* sC  = psC + PSC_ELEMS;
    float* sx  = sC + 1024;

    k1_reduce  <<<dim3(1536),    256, 0, stream>>>(x4, psx, (f4*)psC);
    k1_reduce_C<<<dim3(96),      256, 0, stream>>>(C4, (f4*)psC);
    k2_finalize<<<dim3(136),     128, 0, stream>>>(psx, psC, sx, sC);
    k3_expand  <<<dim3(16, 128), 256, 0, stream>>>(sx, sC, (f4*)d_out);
}